// Round 7
// baseline (3667.860 us; speedup 1.0000x reference)
//
#include <hip/hip_runtime.h>
#include <stdint.h>

#define NROWS 131072
#define NC 1024
#define ND 512
#define BM 64
#define NSTEP 32   // 16 K-steps x {hi, lo} B-tables

using f32x4   = __attribute__((ext_vector_type(4))) float;
using bf16x8  = __attribute__((ext_vector_type(8))) short;
using float4v = __attribute__((ext_vector_type(4))) float;

#define WAITV8() asm volatile("s_waitcnt vmcnt(8)" ::: "memory")
#define WAITV0() asm volatile("s_waitcnt vmcnt(0)" ::: "memory")

__device__ __forceinline__ uint16_t f32_bf16(float f) {
  uint32_t u = __builtin_bit_cast(uint32_t, f);
  u += 0x7FFFu + ((u >> 16) & 1u);   // RNE
  return (uint16_t)(u >> 16);
}
__device__ __forceinline__ float bf16_f32(uint16_t h) {
  uint32_t u = ((uint32_t)h) << 16;
  return __builtin_bit_cast(float, u);
}

__device__ __forceinline__ void gload_lds16(const void* g, void* l) {
  __builtin_amdgcn_global_load_lds(
      (const __attribute__((address_space(1))) unsigned int*)g,
      (__attribute__((address_space(3))) unsigned int*)l, 16, 0, 0);
}

// ---------------------------------------------------------------------------
// Prep: split centers into bf16 hi/lo, pre-permuted so each 32-k slice is a
// contiguous 64KB block whose LINEAR copy into LDS yields the swizzled layout:
// LDS[c*64 + p*16 + b] holds logical 16B chunk j = p ^ ((c>>1)&3) of row c.
// (proven round 5: bank conflicts 5.0e7 -> 4.2e6). Also computes csq[c].
// ---------------------------------------------------------------------------
__global__ __launch_bounds__(64) void prep_centers(
    const float* __restrict__ centers,
    uint16_t* __restrict__ cs_hi, uint16_t* __restrict__ cs_lo,
    float* __restrict__ csq) {
  const int c = blockIdx.x;   // 1024
  const int t = threadIdx.x;  // 64
  const float* row = centers + (size_t)c * ND;
  const int k0 = t * 8;
  float v[8];
#pragma unroll
  for (int i = 0; i < 8; ++i) v[i] = row[k0 + i];
  float ss = 0.f;
#pragma unroll
  for (int i = 0; i < 8; ++i) ss += v[i] * v[i];
#pragma unroll
  for (int m = 1; m < 64; m <<= 1) ss += __shfl_xor(ss, m);
  if (t == 0) csq[c] = ss;

  const int kk = t >> 2;               // K-step 0..15
  const int j  = t & 3;                // logical 16B chunk within K-step
  const int p  = j ^ ((c >> 1) & 3);   // physical chunk (XOR swizzle)
  const size_t off = (size_t)kk * 32768 + (size_t)c * 32 + (size_t)p * 8;
#pragma unroll
  for (int i = 0; i < 8; ++i) {
    uint16_t h = f32_bf16(v[i]);
    uint16_t l = f32_bf16(v[i] - bf16_f32(h));
    cs_hi[off + i] = h;
    cs_lo[off + i] = l;
  }
}

// ---------------------------------------------------------------------------
// Fused kernel: 64 rows x 1024 cols per block, 1024 thr / 16 waves (2 wm x
// 8 wn, wave tile 32x128, acc[2][8] = 64 regs -> proven no-spill point).
// B double-buffered 2x64KB staged via global_load_lds kept in flight across
// raw s_barriers with counted vmcnt(8) (T3/T4); 4 waves/SIMD hide the rest.
// A direct-to-reg from global, hi/lo split inline; xsq folded in. T5 setprio.
// Pass H (s<16): B=cs_hi, acc += a_hi*b + a_lo*b
// Pass L (s>=16): B=cs_lo, acc += a_hi*b
// Epilogue: LDS transpose, one wave per row, contiguous float4 stores.
// ---------------------------------------------------------------------------
__global__ __launch_bounds__(1024) void kmeans_fused(
    const float* __restrict__ x,
    const uint16_t* __restrict__ cs_hi, const uint16_t* __restrict__ cs_lo,
    const float* __restrict__ csq,
    float* __restrict__ dist, float* __restrict__ prob) {
  __shared__ __align__(16) char bs[2][65536];   // 1024 cols x 32 bf16, swizzled
  __shared__ float xsq[BM];

  const int tid  = threadIdx.x;
  const int lane = tid & 63;
  const int wid  = tid >> 6;        // 0..15
  const int wm   = wid >> 3;        // 0..1 -> rows wm*32
  const int wn   = wid & 7;         // 0..7 -> cols wn*128
  const int row0 = blockIdx.x * BM;
  const int arow = lane & 15;       // A fragment row (mr=0); mr=1 adds 16
  const int kq   = lane >> 4;       // k-quarter 0..3

  const float* xa0 = x + (size_t)(row0 + wm * 32 + arow) * ND + kq * 8;
  const float* xa1 = xa0 + (size_t)16 * ND;

  auto stage = [&](int s) {
    const uint16_t* base = (s < 16) ? cs_hi : cs_lo;
    const char* srcb = (const char*)(base + (size_t)(s & 15) * 32768);
    char* dst = bs[s & 1];
    const int o = tid * 16;
#pragma unroll
    for (int i = 0; i < 4; ++i)
      gload_lds16(srcb + o + i * 16384, dst + o + i * 16384);
  };

  f32x4 acc[2][8];
  const f32x4 z = {0.f, 0.f, 0.f, 0.f};
#pragma unroll
  for (int mr = 0; mr < 2; ++mr)
#pragma unroll
    for (int n = 0; n < 8; ++n) acc[mr][n] = z;

  // B fragment LDS byte offset (col = wn*128 + arow + n*16; bases mult of 16
  // so (col>>1)&3 == (arow>>1)&3)
  const int swz  = ((kq ^ ((arow >> 1) & 3)) << 4);
  const int boff = (wn * 128 + arow) * 64 + swz;

  float xacc0 = 0.f, xacc1 = 0.f;

  // cvt batch -> frags (hi always; lo + xsq only for pass H)
  bf16x8 ah0, ah1, al0, al1;
  auto cvt = [&](int s, const float4v& a0a, const float4v& a0b,
                 const float4v& a1a, const float4v& a1b) {
    float v0[8] = {a0a[0], a0a[1], a0a[2], a0a[3], a0b[0], a0b[1], a0b[2], a0b[3]};
    float v1[8] = {a1a[0], a1a[1], a1a[2], a1a[3], a1b[0], a1b[1], a1b[2], a1b[3]};
#pragma unroll
    for (int i = 0; i < 8; ++i) {
      ah0[i] = (short)f32_bf16(v0[i]);
      ah1[i] = (short)f32_bf16(v1[i]);
    }
    if (s < 16) {
#pragma unroll
      for (int i = 0; i < 8; ++i) {
        al0[i] = (short)f32_bf16(v0[i] - bf16_f32((uint16_t)(unsigned short)ah0[i]));
        al1[i] = (short)f32_bf16(v1[i] - bf16_f32((uint16_t)(unsigned short)ah1[i]));
        xacc0 += v0[i] * v0[i];
        xacc1 += v1[i] * v1[i];
      }
    }
  };

  auto compute = [&](int s) {
    const char* bp = bs[s & 1];
    __builtin_amdgcn_s_setprio(1);
    if (s < 16) {
#pragma unroll
      for (int n = 0; n < 8; ++n) {
        bf16x8 b = *(const bf16x8*)(bp + boff + n * 1024);
        acc[0][n] = __builtin_amdgcn_mfma_f32_16x16x32_bf16(ah0, b, acc[0][n], 0, 0, 0);
        acc[1][n] = __builtin_amdgcn_mfma_f32_16x16x32_bf16(ah1, b, acc[1][n], 0, 0, 0);
        acc[0][n] = __builtin_amdgcn_mfma_f32_16x16x32_bf16(al0, b, acc[0][n], 0, 0, 0);
        acc[1][n] = __builtin_amdgcn_mfma_f32_16x16x32_bf16(al1, b, acc[1][n], 0, 0, 0);
      }
    } else {
#pragma unroll
      for (int n = 0; n < 8; ++n) {
        bf16x8 b = *(const bf16x8*)(bp + boff + n * 1024);
        acc[0][n] = __builtin_amdgcn_mfma_f32_16x16x32_bf16(ah0, b, acc[0][n], 0, 0, 0);
        acc[1][n] = __builtin_amdgcn_mfma_f32_16x16x32_bf16(ah1, b, acc[1][n], 0, 0, 0);
      }
    }
    __builtin_amdgcn_s_setprio(0);
  };

  // ---- prologue: batch 0 in flight (4 stage + 4 A loads = 8 vmem ops) ----
  float4v Ax0a, Ax0b, Ax1a, Ax1b;   // even-step A batch
  float4v Ay0a, Ay0b, Ay1a, Ay1b;   // odd-step A batch
  stage(0);
  Ax0a = *(const float4v*)xa0;      Ax0b = *(const float4v*)(xa0 + 4);
  Ax1a = *(const float4v*)xa1;      Ax1b = *(const float4v*)(xa1 + 4);

  // ---- main loop, unrolled x2 (static A ping-pong, rule #20) ----
#pragma unroll 1
  for (int s2 = 0; s2 < NSTEP; s2 += 2) {
    // even step s2: consume Ax, prefetch batch s2+1 -> Ay
    {
      const int sn = s2 + 1;
      stage(sn);
      const float* p0 = xa0 + (sn & 15) * 32;
      const float* p1 = xa1 + (sn & 15) * 32;
      Ay0a = *(const float4v*)p0;   Ay0b = *(const float4v*)(p0 + 4);
      Ay1a = *(const float4v*)p1;   Ay1b = *(const float4v*)(p1 + 4);
      WAITV8();                     // batch s2 (8 oldest) complete
      cvt(s2, Ax0a, Ax0b, Ax1a, Ax1b);
      __builtin_amdgcn_s_barrier(); // bs[s2&1] ready for all waves
      compute(s2);
      __builtin_amdgcn_s_barrier(); // reads done before overwrite
    }
    // odd step s2+1: consume Ay, prefetch batch s2+2 -> Ax
    {
      const int s = s2 + 1;
      const int sn = s2 + 2;
      if (sn < NSTEP) {
        stage(sn);
        const float* p0 = xa0 + (sn & 15) * 32;
        const float* p1 = xa1 + (sn & 15) * 32;
        Ax0a = *(const float4v*)p0; Ax0b = *(const float4v*)(p0 + 4);
        Ax1a = *(const float4v*)p1; Ax1b = *(const float4v*)(p1 + 4);
        WAITV8();
      } else {
        WAITV0();
      }
      cvt(s, Ay0a, Ay0b, Ay1a, Ay1b);
      __builtin_amdgcn_s_barrier();
      compute(s);
      __builtin_amdgcn_s_barrier();
    }
  }

  // ---- xsq: reduce k-quarters (lanes l, l+16, l+32, l+48 share a row) ----
  xacc0 += __shfl_xor(xacc0, 16);
  xacc0 += __shfl_xor(xacc0, 32);
  xacc1 += __shfl_xor(xacc1, 16);
  xacc1 += __shfl_xor(xacc1, 32);
  if (wn == 0 && lane < 16) {
    xsq[wm * 32 + arow] = xacc0;
    xsq[wm * 32 + arow + 16] = xacc1;
  }

  // ---- epilogue: LDS transpose (16 rows/pass, 4 passes), 1 wave per row ----
  float* ldsT = (float*)bs;   // 16 x 1024 fp32 = 64KB
  const int rsub = (lane >> 4) * 4;
#pragma unroll
  for (int g = 0; g < 4; ++g) {
    if (wm == (g >> 1)) {
      const int p = g & 1;
#pragma unroll
      for (int n = 0; n < 8; ++n)
#pragma unroll
        for (int r = 0; r < 4; ++r) {
          const int lrow = rsub + r;
          const int col = wn * 128 + n * 16 + arow;
          ldsT[lrow * 1024 + (col ^ (((lrow >> 2) & 3) << 3))] = acc[p][n][r];
        }
    }
    __syncthreads();
    {
      const int lr = wid;                  // one wave per row
      const size_t grow = (size_t)(row0 + g * 16 + lr);
      const int cmask = ((lr >> 2) & 3) << 3;
      const float xq = xsq[g * 16 + lr];
      float4v dd[4];
      float dmin = 1e30f;
#pragma unroll
      for (int j = 0; j < 4; ++j) {
        const int f = lane * 4 + j * 256;
        float4v raw = *(const float4v*)&ldsT[lr * 1024 + (f ^ cmask)];
        float4v cq = *(const float4v*)(csq + f);
#pragma unroll
        for (int i = 0; i < 4; ++i) {
          float d = fmaxf(xq + cq[i] - 2.0f * raw[i], 0.0f);
          dd[j][i] = d;
          dmin = fminf(dmin, d);
        }
      }
#pragma unroll
      for (int m = 1; m < 64; m <<= 1) dmin = fminf(dmin, __shfl_xor(dmin, m));
#pragma unroll
      for (int j = 0; j < 4; ++j)
        *(float4v*)(dist + grow * NC + lane * 4 + j * 256) = dd[j];
      float ssum = 0.f;
#pragma unroll
      for (int j = 0; j < 4; ++j)
#pragma unroll
        for (int i = 0; i < 4; ++i) {
          float e = __expf(dmin - dd[j][i]);
          dd[j][i] = e;
          ssum += e;
        }
#pragma unroll
      for (int m = 1; m < 64; m <<= 1) ssum += __shfl_xor(ssum, m);
      const float sinv = 1.0f / ssum;
#pragma unroll
      for (int j = 0; j < 4; ++j) {
        float4v pv;
#pragma unroll
        for (int i = 0; i < 4; ++i) pv[i] = dd[j][i] * sinv;
        *(float4v*)(prob + grow * NC + lane * 4 + j * 256) = pv;
      }
    }
    __syncthreads();
  }
}

extern "C" void kernel_launch(void* const* d_in, const int* in_sizes, int n_in,
                              void* d_out, int out_size, void* d_ws, size_t ws_size,
                              hipStream_t stream) {
  const float* x = (const float*)d_in[0];
  const float* centers = (const float*)d_in[1];
  float* dist = (float*)d_out;
  float* prob = dist + (size_t)NROWS * NC;

  uint16_t* cs_hi = (uint16_t*)d_ws;                 // 1 MB
  uint16_t* cs_lo = cs_hi + (size_t)NC * ND;         // 1 MB
  float* csq = (float*)(cs_lo + (size_t)NC * ND);    // 4 KB

  prep_centers<<<dim3(NC), dim3(64), 0, stream>>>(centers, cs_hi, cs_lo, csq);
  kmeans_fused<<<dim3(NROWS / BM), dim3(1024), 0, stream>>>(x, cs_hi, cs_lo, csq,
                                                            dist, prob);
}

// Round 8
// 1094.586 us; speedup vs baseline: 3.3509x; 3.3509x over previous
//
#include <hip/hip_runtime.h>
#include <stdint.h>

#define NROWS 131072
#define NC 1024
#define ND 512
#define BM 128
#define BN 256
#define NPANEL 4
#define NSTEP 32   // 16 K-steps x {hi, lo} B-tables

using f32x4   = __attribute__((ext_vector_type(4))) float;
using bf16x8  = __attribute__((ext_vector_type(8))) short;
using float4v = __attribute__((ext_vector_type(4))) float;

#define WAITV6() asm volatile("s_waitcnt vmcnt(6)" ::: "memory")
#define WAITV0() asm volatile("s_waitcnt vmcnt(0)" ::: "memory")

__device__ __forceinline__ uint16_t f32_bf16(float f) {
  uint32_t u = __builtin_bit_cast(uint32_t, f);
  u += 0x7FFFu + ((u >> 16) & 1u);   // RNE
  return (uint16_t)(u >> 16);
}
__device__ __forceinline__ float bf16_f32(uint16_t h) {
  uint32_t u = ((uint32_t)h) << 16;
  return __builtin_bit_cast(float, u);
}

__device__ __forceinline__ void gload_lds16(const void* g, void* l) {
  __builtin_amdgcn_global_load_lds(
      (const __attribute__((address_space(1))) unsigned int*)g,
      (__attribute__((address_space(3))) unsigned int*)l, 16, 0, 0);
}

// ---------------------------------------------------------------------------
// Prep: split centers into bf16 hi/lo, laid out per (panel, K-step) as a
// contiguous 16KB block whose LINEAR LDS copy yields the swizzled layout:
// LDS[c*64 + p*16 + b], p = j ^ ((c>>1)&3)  (proven swizzle, 12x fewer
// bank conflicts). Layout: [panel 0..3][kstep 0..15][256 cols x 32k].
// Also computes csq[c] in fp32.
// ---------------------------------------------------------------------------
__global__ __launch_bounds__(64) void prep_centers(
    const float* __restrict__ centers,
    uint16_t* __restrict__ cs_hi, uint16_t* __restrict__ cs_lo,
    float* __restrict__ csq) {
  const int c = blockIdx.x;   // 1024
  const int t = threadIdx.x;  // 64
  const float* row = centers + (size_t)c * ND;
  float v[8];
#pragma unroll
  for (int i = 0; i < 8; ++i) v[i] = row[t * 8 + i];
  float ss = 0.f;
#pragma unroll
  for (int i = 0; i < 8; ++i) ss += v[i] * v[i];
#pragma unroll
  for (int m = 1; m < 64; m <<= 1) ss += __shfl_xor(ss, m);
  if (t == 0) csq[c] = ss;

  const int panel = c >> 8;             // 0..3
  const int cw = c & 255;               // col within panel
  const int kk = t >> 2;                // K-step 0..15
  const int j  = t & 3;                 // logical 16B chunk
  const int p  = j ^ ((cw >> 1) & 3);   // physical chunk (XOR swizzle)
  const size_t off = (size_t)(panel * 16 + kk) * 8192 + (size_t)cw * 32 + (size_t)p * 8;
#pragma unroll
  for (int i = 0; i < 8; ++i) {
    uint16_t h = f32_bf16(v[i]);
    uint16_t l = f32_bf16(v[i] - bf16_f32(h));
    cs_hi[off + i] = h;
    cs_lo[off + i] = l;
  }
}

// ---------------------------------------------------------------------------
// Phase 1: distances only. Block = 128 rows x 256 cols, 512 thr / 8 waves
// (4 wm x 2 wn, wave tile 32x128, acc[2][8] = 64 regs -> proven no-spill).
// Stage 16KB/step (293cyc) vs 256 MFMA/step/CU (1242cyc) -> compute-bound.
// B dbuf 2x16KB via global_load_lds held in flight across raw s_barriers
// with counted vmcnt(6); A direct-to-reg; xsq fused. LDS ~66KB -> 2 blk/CU.
// Epilogue: LDS transpose (stride 260 pad) -> contiguous 1KB dist rows.
// ---------------------------------------------------------------------------
__global__ __launch_bounds__(512) void kmeans_dist(
    const float* __restrict__ x,
    const uint16_t* __restrict__ cs_hi, const uint16_t* __restrict__ cs_lo,
    const float* __restrict__ csq,
    float* __restrict__ dist) {
  __shared__ __align__(16) char bs[2][16384];    // 256 cols x 32 bf16, swizzled
  __shared__ __align__(16) float ldsT[32][260];  // transpose buffer (+4 pad)
  __shared__ float xsq[BM];

  const int tid  = threadIdx.x;
  const int lane = tid & 63;
  const int wid  = tid >> 6;        // 0..7
  const int wm   = wid >> 1;        // 0..3 -> rows wm*32
  const int wn   = wid & 1;         // 0..1 -> cols wn*128
  const int rg   = blockIdx.x >> 2; // row group (128 rows)
  const int panel = blockIdx.x & 3; // 256-col panel
  const int row0 = rg * BM;
  const int arow = lane & 15;       // A fragment row (mr=0); mr=1 adds 16
  const int kq   = lane >> 4;       // k-quarter 0..3

  const float* xa0 = x + (size_t)(row0 + wm * 32 + arow) * ND + kq * 8;
  const float* xa1 = xa0 + (size_t)16 * ND;

  auto stage = [&](int s) {
    const uint16_t* base = (s < 16) ? cs_hi : cs_lo;
    const char* srcb = (const char*)(base + (size_t)(panel * 16 + (s & 15)) * 8192);
    char* dst = bs[s & 1];
    const int o = tid * 16;
    gload_lds16(srcb + o, dst + o);
    gload_lds16(srcb + o + 8192, dst + o + 8192);
  };

  f32x4 acc[2][8];
  const f32x4 z = {0.f, 0.f, 0.f, 0.f};
#pragma unroll
  for (int mr = 0; mr < 2; ++mr)
#pragma unroll
    for (int n = 0; n < 8; ++n) acc[mr][n] = z;

  // B fragment LDS byte offset (col = wn*128 + n*16 + arow; (col>>1)&3 ==
  // (arow>>1)&3 since other terms are multiples of 16)
  const int swz  = ((kq ^ ((arow >> 1) & 3)) << 4);
  const int boff = (wn * 128 + arow) * 64 + swz;   // + n*1024

  float xacc0 = 0.f, xacc1 = 0.f;

  bf16x8 ah0, ah1, al0, al1;
  auto cvt = [&](int s, const float4v& a0a, const float4v& a0b,
                 const float4v& a1a, const float4v& a1b) {
    float v0[8] = {a0a[0], a0a[1], a0a[2], a0a[3], a0b[0], a0b[1], a0b[2], a0b[3]};
    float v1[8] = {a1a[0], a1a[1], a1a[2], a1a[3], a1b[0], a1b[1], a1b[2], a1b[3]};
#pragma unroll
    for (int i = 0; i < 8; ++i) {
      ah0[i] = (short)f32_bf16(v0[i]);
      ah1[i] = (short)f32_bf16(v1[i]);
    }
    if (s < 16) {
#pragma unroll
      for (int i = 0; i < 8; ++i) {
        al0[i] = (short)f32_bf16(v0[i] - bf16_f32((uint16_t)(unsigned short)ah0[i]));
        al1[i] = (short)f32_bf16(v1[i] - bf16_f32((uint16_t)(unsigned short)ah1[i]));
        xacc0 += v0[i] * v0[i];
        xacc1 += v1[i] * v1[i];
      }
    }
  };

  auto compute = [&](int s) {
    const char* bp = bs[s & 1];
    __builtin_amdgcn_s_setprio(1);
    if (s < 16) {
#pragma unroll
      for (int n = 0; n < 8; ++n) {
        bf16x8 b = *(const bf16x8*)(bp + boff + n * 1024);
        acc[0][n] = __builtin_amdgcn_mfma_f32_16x16x32_bf16(ah0, b, acc[0][n], 0, 0, 0);
        acc[1][n] = __builtin_amdgcn_mfma_f32_16x16x32_bf16(ah1, b, acc[1][n], 0, 0, 0);
        acc[0][n] = __builtin_amdgcn_mfma_f32_16x16x32_bf16(al0, b, acc[0][n], 0, 0, 0);
        acc[1][n] = __builtin_amdgcn_mfma_f32_16x16x32_bf16(al1, b, acc[1][n], 0, 0, 0);
      }
    } else {
#pragma unroll
      for (int n = 0; n < 8; ++n) {
        bf16x8 b = *(const bf16x8*)(bp + boff + n * 1024);
        acc[0][n] = __builtin_amdgcn_mfma_f32_16x16x32_bf16(ah0, b, acc[0][n], 0, 0, 0);
        acc[1][n] = __builtin_amdgcn_mfma_f32_16x16x32_bf16(ah1, b, acc[1][n], 0, 0, 0);
      }
    }
    __builtin_amdgcn_s_setprio(0);
  };

  // ---- prologue: batch 0 in flight (2 stage + 4 A loads = 6 vmem ops) ----
  float4v Ax0a, Ax0b, Ax1a, Ax1b;
  float4v Ay0a, Ay0b, Ay1a, Ay1b;
  stage(0);
  Ax0a = *(const float4v*)xa0;      Ax0b = *(const float4v*)(xa0 + 4);
  Ax1a = *(const float4v*)xa1;      Ax1b = *(const float4v*)(xa1 + 4);

  // ---- main loop, unrolled x2 (static A ping-pong, rule #20) ----
#pragma unroll 1
  for (int s2 = 0; s2 < NSTEP; s2 += 2) {
    {
      const int sn = s2 + 1;
      stage(sn);
      const float* p0 = xa0 + (sn & 15) * 32;
      const float* p1 = xa1 + (sn & 15) * 32;
      Ay0a = *(const float4v*)p0;   Ay0b = *(const float4v*)(p0 + 4);
      Ay1a = *(const float4v*)p1;   Ay1b = *(const float4v*)(p1 + 4);
      WAITV6();                     // batch s2 (6 oldest) complete
      cvt(s2, Ax0a, Ax0b, Ax1a, Ax1b);
      __builtin_amdgcn_s_barrier(); // bs[s2&1] ready for all waves
      compute(s2);
      __builtin_amdgcn_s_barrier(); // reads done before overwrite
    }
    {
      const int s = s2 + 1;
      const int sn = s2 + 2;
      if (sn < NSTEP) {
        stage(sn);
        const float* p0 = xa0 + (sn & 15) * 32;
        const float* p1 = xa1 + (sn & 15) * 32;
        Ax0a = *(const float4v*)p0; Ax0b = *(const float4v*)(p0 + 4);
        Ax1a = *(const float4v*)p1; Ax1b = *(const float4v*)(p1 + 4);
        WAITV6();
      } else {
        WAITV0();
      }
      cvt(s, Ay0a, Ay0b, Ay1a, Ay1b);
      __builtin_amdgcn_s_barrier();
      compute(s);
      __builtin_amdgcn_s_barrier();
    }
  }

  // ---- xsq: reduce k-quarters (lanes l, l+16, l+32, l+48 share a row) ----
  xacc0 += __shfl_xor(xacc0, 16);
  xacc0 += __shfl_xor(xacc0, 32);
  xacc1 += __shfl_xor(xacc1, 16);
  xacc1 += __shfl_xor(xacc1, 32);
  if (wn == 0 && lane < 16) {
    xsq[wm * 32 + arow] = xacc0;
    xsq[wm * 32 + arow + 16] = xacc1;
  }

  // csq for this panel (one float4 per lane)
  const float4v cq = *(const float4v*)(csq + panel * BN + lane * 4);

  // ---- epilogue: 4 transpose passes (32 rows each), contiguous stores ----
  const int rsub = (lane >> 4) * 4;
#pragma unroll
  for (int g = 0; g < 4; ++g) {
    if (wm == g) {
#pragma unroll
      for (int mr = 0; mr < 2; ++mr)
#pragma unroll
        for (int n = 0; n < 8; ++n)
#pragma unroll
          for (int rr = 0; rr < 4; ++rr)
            ldsT[mr * 16 + rsub + rr][wn * 128 + n * 16 + arow] = acc[mr][n][rr];
    }
    __syncthreads();
    {
      const int lr = wid * 4;     // 4 rows per wave
#pragma unroll
      for (int q = 0; q < 4; ++q) {
        const int r = lr + q;
        const float xq = xsq[g * 32 + r];
        const float4v raw = *(const float4v*)&ldsT[r][lane * 4];
        float4v dd;
#pragma unroll
        for (int i = 0; i < 4; ++i)
          dd[i] = fmaxf(xq + cq[i] - 2.0f * raw[i], 0.0f);
        *(float4v*)(dist + (size_t)(row0 + g * 32 + r) * NC + panel * BN + lane * 4) = dd;
      }
    }
    __syncthreads();
  }
}

// ---------------------------------------------------------------------------
// Phase 2: row softmax(-dist) -> prob. One wave per row; contiguous float4
// loads/stores; pure streaming (1.07GB total).
// ---------------------------------------------------------------------------
__global__ __launch_bounds__(512) void softmax_rows(
    const float* __restrict__ dist, float* __restrict__ prob) {
  const int tid  = threadIdx.x;
  const int lane = tid & 63;
  const int wid  = tid >> 6;
  const size_t row = (size_t)blockIdx.x * 8 + wid;
  const float* dp = dist + row * NC;
  float* pp = prob + row * NC;

  float4v dd[4];
#pragma unroll
  for (int j = 0; j < 4; ++j)
    dd[j] = *(const float4v*)(dp + lane * 4 + j * 256);

  float dmin = 1e30f;
#pragma unroll
  for (int j = 0; j < 4; ++j)
#pragma unroll
    for (int i = 0; i < 4; ++i) dmin = fminf(dmin, dd[j][i]);
#pragma unroll
  for (int m = 1; m < 64; m <<= 1) dmin = fminf(dmin, __shfl_xor(dmin, m));

  float ssum = 0.f;
#pragma unroll
  for (int j = 0; j < 4; ++j)
#pragma unroll
    for (int i = 0; i < 4; ++i) {
      float e = __expf(dmin - dd[j][i]);
      dd[j][i] = e;
      ssum += e;
    }
#pragma unroll
  for (int m = 1; m < 64; m <<= 1) ssum += __shfl_xor(ssum, m);
  const float sinv = 1.0f / ssum;

#pragma unroll
  for (int j = 0; j < 4; ++j) {
    float4v pv;
#pragma unroll
    for (int i = 0; i < 4; ++i) pv[i] = dd[j][i] * sinv;
    *(float4v*)(pp + lane * 4 + j * 256) = pv;
  }
}

extern "C" void kernel_launch(void* const* d_in, const int* in_sizes, int n_in,
                              void* d_out, int out_size, void* d_ws, size_t ws_size,
                              hipStream_t stream) {
  const float* x = (const float*)d_in[0];
  const float* centers = (const float*)d_in[1];
  float* dist = (float*)d_out;
  float* prob = dist + (size_t)NROWS * NC;

  uint16_t* cs_hi = (uint16_t*)d_ws;                 // 1 MB
  uint16_t* cs_lo = cs_hi + (size_t)NC * ND;         // 1 MB
  float* csq = (float*)(cs_lo + (size_t)NC * ND);    // 4 KB

  prep_centers<<<dim3(NC), dim3(64), 0, stream>>>(centers, cs_hi, cs_lo, csq);
  kmeans_dist<<<dim3((NROWS / BM) * NPANEL), dim3(512), 0, stream>>>(
      x, cs_hi, cs_lo, csq, dist);
  softmax_rows<<<dim3(NROWS / 8), dim3(512), 0, stream>>>(dist, prob);
}

// Round 9
// 905.116 us; speedup vs baseline: 4.0524x; 1.2093x over previous
//
#include <hip/hip_runtime.h>
#include <stdint.h>

#define NROWS 131072
#define NC 1024
#define ND 512
#define BM 128
#define BN 256
#define NPANEL 4
#define NSTEP 32   // 16 K-steps x {hi, lo} B-tables

using f32x4   = __attribute__((ext_vector_type(4))) float;
using bf16x8  = __attribute__((ext_vector_type(8))) short;
using float4v = __attribute__((ext_vector_type(4))) float;

#define WAITV4() asm volatile("s_waitcnt vmcnt(4)" ::: "memory")
#define WAITV0() asm volatile("s_waitcnt vmcnt(0)" ::: "memory")

__device__ __forceinline__ uint16_t f32_bf16(float f) {
  uint32_t u = __builtin_bit_cast(uint32_t, f);
  u += 0x7FFFu + ((u >> 16) & 1u);   // RNE
  return (uint16_t)(u >> 16);
}
__device__ __forceinline__ float bf16_f32(uint16_t h) {
  uint32_t u = ((uint32_t)h) << 16;
  return __builtin_bit_cast(float, u);
}

__device__ __forceinline__ void gload_lds16(const void* g, void* l) {
  __builtin_amdgcn_global_load_lds(
      (const __attribute__((address_space(1))) unsigned int*)g,
      (__attribute__((address_space(3))) unsigned int*)l, 16, 0, 0);
}

// ---------------------------------------------------------------------------
// Prep: split centers into bf16 hi/lo, laid out per (panel, K-step) as a
// contiguous 16KB block whose LINEAR LDS copy yields the swizzled layout:
// LDS[c*64 + p*16 + b], p = j ^ ((c>>1)&3)  (proven: 0 bank conflicts).
// Layout: [panel 0..3][kstep 0..15][256 cols x 32k]. Also csq[c] in fp32.
// ---------------------------------------------------------------------------
__global__ __launch_bounds__(64) void prep_centers(
    const float* __restrict__ centers,
    uint16_t* __restrict__ cs_hi, uint16_t* __restrict__ cs_lo,
    float* __restrict__ csq) {
  const int c = blockIdx.x;   // 1024
  const int t = threadIdx.x;  // 64
  const float* row = centers + (size_t)c * ND;
  float v[8];
#pragma unroll
  for (int i = 0; i < 8; ++i) v[i] = row[t * 8 + i];
  float ss = 0.f;
#pragma unroll
  for (int i = 0; i < 8; ++i) ss += v[i] * v[i];
#pragma unroll
  for (int m = 1; m < 64; m <<= 1) ss += __shfl_xor(ss, m);
  if (t == 0) csq[c] = ss;

  const int panel = c >> 8;             // 0..3
  const int cw = c & 255;               // col within panel
  const int kk = t >> 2;                // K-step 0..15
  const int j  = t & 3;                 // logical 16B chunk
  const int p  = j ^ ((cw >> 1) & 3);   // physical chunk (XOR swizzle)
  const size_t off = (size_t)(panel * 16 + kk) * 8192 + (size_t)cw * 32 + (size_t)p * 8;
#pragma unroll
  for (int i = 0; i < 8; ++i) {
    uint16_t h = f32_bf16(v[i]);
    uint16_t l = f32_bf16(v[i] - bf16_f32(h));
    cs_hi[off + i] = h;
    cs_lo[off + i] = l;
  }
}

// ---------------------------------------------------------------------------
// Phase 1: distances only. 128 rows x 256 cols per block, 512 thr / 8 waves
// (4 wm x 2 wn, wave tile 32x128, acc[2][8] = 64 AGPR). A staged through LDS
// as fp32 via global_load_lds (keeps loop VGPR <= 64 -> 2 blocks/CU, the
// round-4-proven residency), chunk-XOR (row&7) source permute for 2-way-free
// frag reads. Batch = 4 gload_lds/step, counted vmcnt(4) across raw barriers.
// cvt fp32->bf16 hi/lo after barrier; xsq fused. T5 setprio around MFMA.
// Epilogue: ldsT (unioned over loop smem) transpose -> contiguous stores.
// ---------------------------------------------------------------------------
__global__ __launch_bounds__(512) void kmeans_dist(
    const float* __restrict__ x,
    const uint16_t* __restrict__ cs_hi, const uint16_t* __restrict__ cs_lo,
    const float* __restrict__ csq,
    float* __restrict__ dist) {
  // loop: bs[2] 16KB @0,16384 ; as[2] 16KB @32768,49152. epilogue: ldsT 32x258 f32.
  __shared__ __align__(16) char smem[65536];
  __shared__ float xsq[BM];

  const int tid  = threadIdx.x;
  const int lane = tid & 63;
  const int wid  = tid >> 6;        // 0..7
  const int wm   = wid >> 1;        // 0..3 -> rows wm*32
  const int wn   = wid & 1;         // 0..1 -> cols wn*128
  const int rg   = blockIdx.x >> 2; // row group (128 rows)
  const int panel = blockIdx.x & 3; // 256-col panel
  const int row0 = rg * BM;
  const int arow = lane & 15;       // frag row (mr=0); mr=1 adds 16
  const int kq   = lane >> 4;       // k-quarter 0..3

  auto stageB = [&](int s) {
    const uint16_t* base = (s < 16) ? cs_hi : cs_lo;
    const char* srcb = (const char*)(base + (size_t)(panel * 16 + (s & 15)) * 8192);
    char* dst = smem + (s & 1) * 16384;
    const int o = tid * 16;
    gload_lds16(srcb + o, dst + o);
    gload_lds16(srcb + o + 8192, dst + o + 8192);
  };
  auto stageA = [&](int s) {
    // 128 rows x 32 k fp32, LDS[row][p], p = c ^ (row&7); linear dst,
    // per-lane source picks logical chunk c.
    char* dst = smem + 32768 + (s & 1) * 16384;
    const int kwin = (s & 15) * 32;
#pragma unroll
    for (int i = 0; i < 2; ++i) {
      const int g = i * 512 + tid;       // global 16B chunk 0..1023
      const int r = g >> 3;              // row 0..127
      const int c = (g & 7) ^ (r & 7);   // logical chunk for this slot
      const char* src = (const char*)(x + (size_t)(row0 + r) * ND + kwin + c * 4);
      gload_lds16(src, dst + g * 16);
    }
  };

  f32x4 acc[2][8];
  const f32x4 z = {0.f, 0.f, 0.f, 0.f};
#pragma unroll
  for (int mr = 0; mr < 2; ++mr)
#pragma unroll
    for (int n = 0; n < 8; ++n) acc[mr][n] = z;

  // B fragment LDS byte offset (proven 0-conflict swizzle)
  const int swz  = ((kq ^ ((arow >> 1) & 3)) << 4);
  const int boff = (wn * 128 + arow) * 64 + swz;   // + n*1024
  // A fragment: phys chunk offsets (row&7 == arow&7 for both mr)
  const int pa0 = ((2 * kq) ^ (arow & 7)) * 16;
  const int pa1 = ((2 * kq + 1) ^ (arow & 7)) * 16;
  const int abase = (wm * 32 + arow) * 128;        // + mr*2048

  float xacc0 = 0.f, xacc1 = 0.f;

  // ---- prologue: batch 0 in flight (2 B + 2 A gload_lds) ----
  stageB(0);
  stageA(0);

#pragma unroll 1
  for (int s = 0; s < NSTEP; ++s) {
    if (s + 1 < NSTEP) {
      stageB(s + 1);
      stageA(s + 1);
      WAITV4();                     // batch s (4 oldest) complete
    } else {
      WAITV0();
    }
    __builtin_amdgcn_s_barrier();   // all waves' stage(s) visible

    {
      const char* bp = smem + (s & 1) * 16384;
      const char* ap = smem + 32768 + (s & 1) * 16384;
      float4v a00 = *(const float4v*)(ap + abase + pa0);
      float4v a01 = *(const float4v*)(ap + abase + pa1);
      float4v a10 = *(const float4v*)(ap + abase + 2048 + pa0);
      float4v a11 = *(const float4v*)(ap + abase + 2048 + pa1);
      float v0[8] = {a00[0], a00[1], a00[2], a00[3], a01[0], a01[1], a01[2], a01[3]};
      float v1[8] = {a10[0], a10[1], a10[2], a10[3], a11[0], a11[1], a11[2], a11[3]};
      bf16x8 ah0, ah1, al0, al1;
#pragma unroll
      for (int i = 0; i < 8; ++i) {
        ah0[i] = (short)f32_bf16(v0[i]);
        ah1[i] = (short)f32_bf16(v1[i]);
      }
      if (s < 16) {
#pragma unroll
        for (int i = 0; i < 8; ++i) {
          al0[i] = (short)f32_bf16(v0[i] - bf16_f32((uint16_t)(unsigned short)ah0[i]));
          al1[i] = (short)f32_bf16(v1[i] - bf16_f32((uint16_t)(unsigned short)ah1[i]));
          xacc0 += v0[i] * v0[i];
          xacc1 += v1[i] * v1[i];
        }
        __builtin_amdgcn_s_setprio(1);
#pragma unroll
        for (int n = 0; n < 8; ++n) {
          bf16x8 b = *(const bf16x8*)(bp + boff + n * 1024);
          acc[0][n] = __builtin_amdgcn_mfma_f32_16x16x32_bf16(ah0, b, acc[0][n], 0, 0, 0);
          acc[1][n] = __builtin_amdgcn_mfma_f32_16x16x32_bf16(ah1, b, acc[1][n], 0, 0, 0);
          acc[0][n] = __builtin_amdgcn_mfma_f32_16x16x32_bf16(al0, b, acc[0][n], 0, 0, 0);
          acc[1][n] = __builtin_amdgcn_mfma_f32_16x16x32_bf16(al1, b, acc[1][n], 0, 0, 0);
        }
        __builtin_amdgcn_s_setprio(0);
      } else {
        __builtin_amdgcn_s_setprio(1);
#pragma unroll
        for (int n = 0; n < 8; ++n) {
          bf16x8 b = *(const bf16x8*)(bp + boff + n * 1024);
          acc[0][n] = __builtin_amdgcn_mfma_f32_16x16x32_bf16(ah0, b, acc[0][n], 0, 0, 0);
          acc[1][n] = __builtin_amdgcn_mfma_f32_16x16x32_bf16(ah1, b, acc[1][n], 0, 0, 0);
        }
        __builtin_amdgcn_s_setprio(0);
      }
    }
    __builtin_amdgcn_s_barrier();   // reads done before next overwrite
  }

  // ---- xsq: reduce k-quarters (lanes l, l+16, l+32, l+48 share a row) ----
  xacc0 += __shfl_xor(xacc0, 16);
  xacc0 += __shfl_xor(xacc0, 32);
  xacc1 += __shfl_xor(xacc1, 16);
  xacc1 += __shfl_xor(xacc1, 32);
  if (wn == 0 && lane < 16) {
    xsq[wm * 32 + arow] = xacc0;
    xsq[wm * 32 + 16 + arow] = xacc1;
  }

  // csq for this panel (one float4 per lane)
  const float4v cq = *(const float4v*)(csq + panel * BN + lane * 4);

  // ---- epilogue: 4 transpose passes (32 rows each), contiguous stores ----
  float* ldsT = (float*)smem;   // 32 x 258 fp32 = 33KB (unions over bs/as)
  const int rsub = (lane >> 4) * 4;
#pragma unroll
  for (int g = 0; g < 4; ++g) {
    if (wm == g) {
#pragma unroll
      for (int mr = 0; mr < 2; ++mr)
#pragma unroll
        for (int n = 0; n < 8; ++n)
#pragma unroll
          for (int rr = 0; rr < 4; ++rr)
            ldsT[(mr * 16 + rsub + rr) * 258 + wn * 128 + n * 16 + arow] = acc[mr][n][rr];
    }
    __syncthreads();
    {
      const int lr = wid * 4;     // 4 rows per wave
#pragma unroll
      for (int q = 0; q < 4; ++q) {
        const int r = lr + q;
        const float xq = xsq[g * 32 + r];
        const float4v raw = *(const float4v*)&ldsT[r * 258 + lane * 4];
        float4v dd;
#pragma unroll
        for (int i = 0; i < 4; ++i)
          dd[i] = fmaxf(xq + cq[i] - 2.0f * raw[i], 0.0f);
        *(float4v*)(dist + (size_t)(row0 + g * 32 + r) * NC + panel * BN + lane * 4) = dd;
      }
    }
    __syncthreads();
  }
}

// ---------------------------------------------------------------------------
// Phase 2: row softmax(-dist) -> prob. One wave per row; contiguous float4
// loads/stores; pure streaming (1.07GB total).
// ---------------------------------------------------------------------------
__global__ __launch_bounds__(512) void softmax_rows(
    const float* __restrict__ dist, float* __restrict__ prob) {
  const int tid  = threadIdx.x;
  const int lane = tid & 63;
  const int wid  = tid >> 6;
  const size_t row = (size_t)blockIdx.x * 8 + wid;
  const float* dp = dist + row * NC;
  float* pp = prob + row * NC;

  float4v dd[4];
#pragma unroll
  for (int j = 0; j < 4; ++j)
    dd[j] = *(const float4v*)(dp + lane * 4 + j * 256);

  float dmin = 1e30f;
#pragma unroll
  for (int j = 0; j < 4; ++j)
#pragma unroll
    for (int i = 0; i < 4; ++i) dmin = fminf(dmin, dd[j][i]);
#pragma unroll
  for (int m = 1; m < 64; m <<= 1) dmin = fminf(dmin, __shfl_xor(dmin, m));

  float ssum = 0.f;
#pragma unroll
  for (int j = 0; j < 4; ++j)
#pragma unroll
    for (int i = 0; i < 4; ++i) {
      float e = __expf(dmin - dd[j][i]);
      dd[j][i] = e;
      ssum += e;
    }
#pragma unroll
  for (int m = 1; m < 64; m <<= 1) ssum += __shfl_xor(ssum, m);
  const float sinv = 1.0f / ssum;

#pragma unroll
  for (int j = 0; j < 4; ++j) {
    float4v pv;
#pragma unroll
    for (int i = 0; i < 4; ++i) pv[i] = dd[j][i] * sinv;
    *(float4v*)(pp + lane * 4 + j * 256) = pv;
  }
}

extern "C" void kernel_launch(void* const* d_in, const int* in_sizes, int n_in,
                              void* d_out, int out_size, void* d_ws, size_t ws_size,
                              hipStream_t stream) {
  const float* x = (const float*)d_in[0];
  const float* centers = (const float*)d_in[1];
  float* dist = (float*)d_out;
  float* prob = dist + (size_t)NROWS * NC;

  uint16_t* cs_hi = (uint16_t*)d_ws;                 // 1 MB
  uint16_t* cs_lo = cs_hi + (size_t)NC * ND;         // 1 MB
  float* csq = (float*)(cs_lo + (size_t)NC * ND);    // 4 KB

  prep_centers<<<dim3(NC), dim3(64), 0, stream>>>(centers, cs_hi, cs_lo, csq);
  kmeans_dist<<<dim3((NROWS / BM) * NPANEL), dim3(512), 0, stream>>>(
      x, cs_hi, cs_lo, csq, dist);
  softmax_rows<<<dim3(NROWS / 8), dim3(512), 0, stream>>>(dist, prob);
}

// Round 10
// 868.421 us; speedup vs baseline: 4.2236x; 1.0423x over previous
//
#include <hip/hip_runtime.h>
#include <stdint.h>

#define NROWS 131072
#define NC 1024
#define ND 512
#define BM 128
#define BN 256
#define NPANEL 4
#define NSTEP 32   // 16 K-steps x {hi, lo} B-tables

using f32x4   = __attribute__((ext_vector_type(4))) float;
using bf16x8  = __attribute__((ext_vector_type(8))) short;
using float4v = __attribute__((ext_vector_type(4))) float;

#define WAITV4() asm volatile("s_waitcnt vmcnt(4)" ::: "memory")
#define WAITV0() asm volatile("s_waitcnt vmcnt(0)" ::: "memory")

__device__ __forceinline__ uint16_t f32_bf16(float f) {
  uint32_t u = __builtin_bit_cast(uint32_t, f);
  u += 0x7FFFu + ((u >> 16) & 1u);   // RNE
  return (uint16_t)(u >> 16);
}
__device__ __forceinline__ float bf16_f32(uint16_t h) {
  uint32_t u = ((uint32_t)h) << 16;
  return __builtin_bit_cast(float, u);
}

__device__ __forceinline__ void gload_lds16(const void* g, void* l) {
  __builtin_amdgcn_global_load_lds(
      (const __attribute__((address_space(1))) unsigned int*)g,
      (__attribute__((address_space(3))) unsigned int*)l, 16, 0, 0);
}

// ---------------------------------------------------------------------------
// Prep centers: bf16 hi/lo, per (panel, kstep) contiguous 16KB block whose
// LINEAR LDS copy yields LDS[c*64 + p*16 + b], p = j ^ ((c>>1)&3) (proven:
// 0 bank conflicts). Also csq[c] in fp32.
// ---------------------------------------------------------------------------
__global__ __launch_bounds__(64) void prep_centers(
    const float* __restrict__ centers,
    uint16_t* __restrict__ cs_hi, uint16_t* __restrict__ cs_lo,
    float* __restrict__ csq) {
  const int c = blockIdx.x;   // 1024
  const int t = threadIdx.x;  // 64
  const float* row = centers + (size_t)c * ND;
  float v[8];
#pragma unroll
  for (int i = 0; i < 8; ++i) v[i] = row[t * 8 + i];
  float ss = 0.f;
#pragma unroll
  for (int i = 0; i < 8; ++i) ss += v[i] * v[i];
#pragma unroll
  for (int m = 1; m < 64; m <<= 1) ss += __shfl_xor(ss, m);
  if (t == 0) csq[c] = ss;

  const int panel = c >> 8;
  const int cw = c & 255;
  const int kk = t >> 2;
  const int j  = t & 3;
  const int p  = j ^ ((cw >> 1) & 3);
  const size_t off = (size_t)(panel * 16 + kk) * 8192 + (size_t)cw * 32 + (size_t)p * 8;
#pragma unroll
  for (int i = 0; i < 8; ++i) {
    uint16_t h = f32_bf16(v[i]);
    uint16_t l = f32_bf16(v[i] - bf16_f32(h));
    cs_hi[off + i] = h;
    cs_lo[off + i] = l;
  }
}

// ---------------------------------------------------------------------------
// Prep x: bf16 hi/lo of x in the SAME pre-swizzled layout, blocked per
// (rowgroup rg of 128 rows, kstep): 8KB block [r 0..127][p 0..3][8 bf16],
// p = j ^ ((r>>1)&3). Main loop then stages A with LINEAR gload_lds and
// reads frags with the proven 0-conflict formula. Also xsq[row] (exact f32).
// Scratch lives in the prob half of d_out (rewritten by softmax later).
// ---------------------------------------------------------------------------
__global__ __launch_bounds__(256) void prep_x(
    const float* __restrict__ x, uint16_t* __restrict__ xh,
    uint16_t* __restrict__ xlo, float* __restrict__ xsq) {
  const int rg = blockIdx.x;        // 0..1023
  const int t  = threadIdx.x;       // 0..255
  const int r  = t >> 1;            // 0..127
  const int h  = t & 1;
  const int row = rg * 128 + r;
  const float* rp = x + (size_t)row * ND;
  const int sw = (r >> 1) & 3;
  float ss = 0.f;
#pragma unroll 1
  for (int kk = 0; kk < 16; ++kk) {
    const float* p = rp + kk * 32 + h * 16;
    float4v c0 = *(const float4v*)p;
    float4v c1 = *(const float4v*)(p + 4);
    float4v c2 = *(const float4v*)(p + 8);
    float4v c3 = *(const float4v*)(p + 12);
    float v[16] = {c0[0], c0[1], c0[2], c0[3], c1[0], c1[1], c1[2], c1[3],
                   c2[0], c2[1], c2[2], c2[3], c3[0], c3[1], c3[2], c3[3]};
    bf16x8 hi0, hi1, lo0, lo1;
#pragma unroll
    for (int i = 0; i < 8; ++i) {
      uint16_t hb = f32_bf16(v[i]);
      hi0[i] = (short)hb;
      lo0[i] = (short)f32_bf16(v[i] - bf16_f32(hb));
      uint16_t hb2 = f32_bf16(v[8 + i]);
      hi1[i] = (short)hb2;
      lo1[i] = (short)f32_bf16(v[8 + i] - bf16_f32(hb2));
      ss += v[i] * v[i] + v[8 + i] * v[8 + i];
    }
    uint16_t* bh = xh  + (size_t)(rg * 16 + kk) * 4096 + r * 32;
    uint16_t* bl = xlo + (size_t)(rg * 16 + kk) * 4096 + r * 32;
    *(bf16x8*)(bh + ((2 * h) ^ sw) * 8)     = hi0;
    *(bf16x8*)(bh + ((2 * h + 1) ^ sw) * 8) = hi1;
    *(bf16x8*)(bl + ((2 * h) ^ sw) * 8)     = lo0;
    *(bf16x8*)(bl + ((2 * h + 1) ^ sw) * 8) = lo1;
  }
  ss += __shfl_xor(ss, 1);
  if (h == 0) xsq[row] = ss;
}

// ---------------------------------------------------------------------------
// Phase 1: distances. 128 rows x 256 cols per block, 512 thr / 8 waves
// (4 wm x 2 wn, wave tile 32x128, acc[2][8] = 64 AGPR). ZERO in-loop VALU
// conversion: A and B both pre-split bf16, staged linearly via gload_lds
// (4 ops/step), counted vmcnt(4) across raw barriers, all frag reads via
// the proven 0-conflict swizzle. Loop VGPR ~ frags+addressing -> 2 blk/CU.
// Epilogue: ldsT transpose (unions loop smem) -> contiguous float4 stores.
// ---------------------------------------------------------------------------
__global__ __launch_bounds__(512) void kmeans_dist(
    const float* __restrict__ xsq_g,
    const uint16_t* __restrict__ xh, const uint16_t* __restrict__ xlo,
    const uint16_t* __restrict__ cs_hi, const uint16_t* __restrict__ cs_lo,
    const float* __restrict__ csq,
    float* __restrict__ dist) {
  // bs dbuf @0/16384 (16KB each); ahi dbuf @32768 (8KB each); alo dbuf @49152.
  __shared__ __align__(16) char smem[65536];

  const int tid  = threadIdx.x;
  const int lane = tid & 63;
  const int wid  = tid >> 6;        // 0..7
  const int wm   = wid >> 1;        // 0..3 -> rows wm*32
  const int wn   = wid & 1;         // 0..1 -> cols wn*128
  const int rg   = blockIdx.x >> 2; // row group (128 rows)
  const int panel = blockIdx.x & 3; // 256-col panel
  const int row0 = rg * BM;
  const int arow = lane & 15;
  const int kq   = lane >> 4;

  auto stageB = [&](int s) {
    const uint16_t* base = (s < 16) ? cs_hi : cs_lo;
    const char* srcb = (const char*)(base + (size_t)(panel * 16 + (s & 15)) * 8192);
    char* dst = smem + (s & 1) * 16384;
    const int o = tid * 16;
    gload_lds16(srcb + o, dst + o);
    gload_lds16(srcb + o + 8192, dst + o + 8192);
  };
  auto stageA = [&](int s) {
    const size_t off = (size_t)(rg * 16 + (s & 15)) * 8192 + tid * 16;
    gload_lds16((const char*)xh + off,  smem + 32768 + (s & 1) * 8192 + tid * 16);
    gload_lds16((const char*)xlo + off, smem + 49152 + (s & 1) * 8192 + tid * 16);
  };

  f32x4 acc[2][8];
  const f32x4 z = {0.f, 0.f, 0.f, 0.f};
#pragma unroll
  for (int mr = 0; mr < 2; ++mr)
#pragma unroll
    for (int n = 0; n < 8; ++n) acc[mr][n] = z;

  const int swz  = ((kq ^ ((arow >> 1) & 3)) << 4);
  const int boff = (wn * 128 + arow) * 64 + swz;   // + n*1024
  const int aoff = (wm * 32 + arow) * 64 + swz;    // + mr*1024

  // ---- prologue: batch 0 in flight (2 B + 2 A) ----
  stageB(0);
  stageA(0);

#pragma unroll 1
  for (int s = 0; s < NSTEP; ++s) {
    if (s + 1 < NSTEP) {
      stageB(s + 1);
      stageA(s + 1);
      WAITV4();                     // batch s (4 oldest) complete
    } else {
      WAITV0();
    }
    __builtin_amdgcn_s_barrier();   // stage(s) visible to all waves

    {
      const char* bp  = smem + (s & 1) * 16384;
      const char* ahp = smem + 32768 + (s & 1) * 8192;
      bf16x8 ah0 = *(const bf16x8*)(ahp + aoff);
      bf16x8 ah1 = *(const bf16x8*)(ahp + aoff + 1024);
      __builtin_amdgcn_s_setprio(1);
      if (s < 16) {
        const char* alp = smem + 49152 + (s & 1) * 8192;
        bf16x8 al0 = *(const bf16x8*)(alp + aoff);
        bf16x8 al1 = *(const bf16x8*)(alp + aoff + 1024);
#pragma unroll
        for (int n = 0; n < 8; ++n) {
          bf16x8 b = *(const bf16x8*)(bp + boff + n * 1024);
          acc[0][n] = __builtin_amdgcn_mfma_f32_16x16x32_bf16(ah0, b, acc[0][n], 0, 0, 0);
          acc[1][n] = __builtin_amdgcn_mfma_f32_16x16x32_bf16(ah1, b, acc[1][n], 0, 0, 0);
          acc[0][n] = __builtin_amdgcn_mfma_f32_16x16x32_bf16(al0, b, acc[0][n], 0, 0, 0);
          acc[1][n] = __builtin_amdgcn_mfma_f32_16x16x32_bf16(al1, b, acc[1][n], 0, 0, 0);
        }
      } else {
#pragma unroll
        for (int n = 0; n < 8; ++n) {
          bf16x8 b = *(const bf16x8*)(bp + boff + n * 1024);
          acc[0][n] = __builtin_amdgcn_mfma_f32_16x16x32_bf16(ah0, b, acc[0][n], 0, 0, 0);
          acc[1][n] = __builtin_amdgcn_mfma_f32_16x16x32_bf16(ah1, b, acc[1][n], 0, 0, 0);
        }
      }
      __builtin_amdgcn_s_setprio(0);
    }
    __builtin_amdgcn_s_barrier();   // reads done before next overwrite
  }

  // csq for this panel (one float4 per lane)
  const float4v cq = *(const float4v*)(csq + panel * BN + lane * 4);

  // ---- epilogue: 4 transpose passes (32 rows each), contiguous stores ----
  float* ldsT = (float*)smem;   // 32 x 258 fp32 = 33KB (unions over loop smem)
  const int rsub = (lane >> 4) * 4;
#pragma unroll
  for (int g = 0; g < 4; ++g) {
    if (wm == g) {
#pragma unroll
      for (int mr = 0; mr < 2; ++mr)
#pragma unroll
        for (int n = 0; n < 8; ++n)
#pragma unroll
          for (int rr = 0; rr < 4; ++rr)
            ldsT[(mr * 16 + rsub + rr) * 258 + wn * 128 + n * 16 + arow] = acc[mr][n][rr];
    }
    __syncthreads();
    {
      const int lr = wid * 4;     // 4 rows per wave
#pragma unroll
      for (int q = 0; q < 4; ++q) {
        const int r = lr + q;
        const float xq = xsq_g[row0 + g * 32 + r];
        const float4v raw = *(const float4v*)&ldsT[r * 258 + lane * 4];
        float4v dd;
#pragma unroll
        for (int i = 0; i < 4; ++i)
          dd[i] = fmaxf(xq + cq[i] - 2.0f * raw[i], 0.0f);
        *(float4v*)(dist + (size_t)(row0 + g * 32 + r) * NC + panel * BN + lane * 4) = dd;
      }
    }
    __syncthreads();
  }
}

// ---------------------------------------------------------------------------
// Phase 2: row softmax(-dist) -> prob. One wave per row, contiguous float4.
// ---------------------------------------------------------------------------
__global__ __launch_bounds__(512) void softmax_rows(
    const float* __restrict__ dist, float* __restrict__ prob) {
  const int tid  = threadIdx.x;
  const int lane = tid & 63;
  const int wid  = tid >> 6;
  const size_t row = (size_t)blockIdx.x * 8 + wid;
  const float* dp = dist + row * NC;
  float* pp = prob + row * NC;

  float4v dd[4];
#pragma unroll
  for (int j = 0; j < 4; ++j)
    dd[j] = *(const float4v*)(dp + lane * 4 + j * 256);

  float dmin = 1e30f;
#pragma unroll
  for (int j = 0; j < 4; ++j)
#pragma unroll
    for (int i = 0; i < 4; ++i) dmin = fminf(dmin, dd[j][i]);
#pragma unroll
  for (int m = 1; m < 64; m <<= 1) dmin = fminf(dmin, __shfl_xor(dmin, m));

  float ssum = 0.f;
#pragma unroll
  for (int j = 0; j < 4; ++j)
#pragma unroll
    for (int i = 0; i < 4; ++i) {
      float e = __expf(dmin - dd[j][i]);
      dd[j][i] = e;
      ssum += e;
    }
#pragma unroll
  for (int m = 1; m < 64; m <<= 1) ssum += __shfl_xor(ssum, m);
  const float sinv = 1.0f / ssum;

#pragma unroll
  for (int j = 0; j < 4; ++j) {
    float4v pv;
#pragma unroll
    for (int i = 0; i < 4; ++i) pv[i] = dd[j][i] * sinv;
    *(float4v*)(pp + lane * 4 + j * 256) = pv;
  }
}

extern "C" void kernel_launch(void* const* d_in, const int* in_sizes, int n_in,
                              void* d_out, int out_size, void* d_ws, size_t ws_size,
                              hipStream_t stream) {
  const float* x = (const float*)d_in[0];
  const float* centers = (const float*)d_in[1];
  float* dist = (float*)d_out;
  float* prob = dist + (size_t)NROWS * NC;

  // x_hi/x_lo/xsq scratch lives in the prob half of d_out (536MB): written by
  // prep_x, consumed by kmeans_dist, then fully overwritten by softmax_rows.
  uint16_t* xh  = (uint16_t*)prob;                       // 134 MB
  uint16_t* xlo = xh + (size_t)NROWS * ND;               // 134 MB
  float* xsq    = (float*)(xlo + (size_t)NROWS * ND);    // 512 KB

  uint16_t* cs_hi = (uint16_t*)d_ws;                     // 1 MB
  uint16_t* cs_lo = cs_hi + (size_t)NC * ND;             // 1 MB
  float* csq = (float*)(cs_lo + (size_t)NC * ND);        // 4 KB

  prep_centers<<<dim3(NC), dim3(64), 0, stream>>>(centers, cs_hi, cs_lo, csq);
  prep_x<<<dim3(NROWS / 128), dim3(256), 0, stream>>>(x, xh, xlo, xsq);
  kmeans_dist<<<dim3((NROWS / BM) * NPANEL), dim3(512), 0, stream>>>(
      xsq, xh, xlo, cs_hi, cs_lo, csq, dist);
  softmax_rows<<<dim3(NROWS / 8), dim3(512), 0, stream>>>(dist, prob);
}

// Round 11
// 856.602 us; speedup vs baseline: 4.2819x; 1.0138x over previous
//
#include <hip/hip_runtime.h>
#include <stdint.h>

#define NROWS 131072
#define NC 1024
#define ND 512
#define BM 128
#define BN 256
#define NPANEL 4
#define NSTEP 32   // 16 K-steps x {hi, lo} B-tables

using f32x4   = __attribute__((ext_vector_type(4))) float;
using bf16x8  = __attribute__((ext_vector_type(8))) short;
using float4v = __attribute__((ext_vector_type(4))) float;

#define WAITV4() asm volatile("s_waitcnt vmcnt(4)" ::: "memory")
#define WAITV0() asm volatile("s_waitcnt vmcnt(0)" ::: "memory")

__device__ __forceinline__ uint16_t f32_bf16(float f) {
  uint32_t u = __builtin_bit_cast(uint32_t, f);
  u += 0x7FFFu + ((u >> 16) & 1u);   // RNE
  return (uint16_t)(u >> 16);
}
__device__ __forceinline__ float bf16_f32(uint16_t h) {
  uint32_t u = ((uint32_t)h) << 16;
  return __builtin_bit_cast(float, u);
}

__device__ __forceinline__ void gload_lds16(const void* g, void* l) {
  __builtin_amdgcn_global_load_lds(
      (const __attribute__((address_space(1))) unsigned int*)g,
      (__attribute__((address_space(3))) unsigned int*)l, 16, 0, 0);
}

// ---------------------------------------------------------------------------
// Prep centers: bf16 hi/lo, per (panel, kstep) contiguous 16KB block whose
// LINEAR LDS copy yields LDS[c*64 + p*16 + b], p = j ^ ((c>>1)&3) (proven:
// 0 bank conflicts). Also csq[c] in fp32.
// ---------------------------------------------------------------------------
__global__ __launch_bounds__(64) void prep_centers(
    const float* __restrict__ centers,
    uint16_t* __restrict__ cs_hi, uint16_t* __restrict__ cs_lo,
    float* __restrict__ csq) {
  const int c = blockIdx.x;   // 1024
  const int t = threadIdx.x;  // 64
  const float* row = centers + (size_t)c * ND;
  float v[8];
#pragma unroll
  for (int i = 0; i < 8; ++i) v[i] = row[t * 8 + i];
  float ss = 0.f;
#pragma unroll
  for (int i = 0; i < 8; ++i) ss += v[i] * v[i];
#pragma unroll
  for (int m = 1; m < 64; m <<= 1) ss += __shfl_xor(ss, m);
  if (t == 0) csq[c] = ss;

  const int panel = c >> 8;
  const int cw = c & 255;
  const int kk = t >> 2;
  const int j  = t & 3;
  const int p  = j ^ ((cw >> 1) & 3);
  const size_t off = (size_t)(panel * 16 + kk) * 8192 + (size_t)cw * 32 + (size_t)p * 8;
#pragma unroll
  for (int i = 0; i < 8; ++i) {
    uint16_t h = f32_bf16(v[i]);
    uint16_t l = f32_bf16(v[i] - bf16_f32(h));
    cs_hi[off + i] = h;
    cs_lo[off + i] = l;
  }
}

// ---------------------------------------------------------------------------
// Prep x v2 (fully coalesced): block = one rowgroup (128 rows), 512 threads.
// Thread t -> (r = t>>2, q = t&3). Per kk-window: reads are dense 128B lines
// (4 threads x 32B cover each row's 128B window), writes are contiguous 8KB
// runs per (rg,kk) block: element offset (rg*16+kk)*4096 + r*32 + p*8,
// p = q ^ ((r>>1)&3) -- bit-identical layout to what kmeans_dist stages
// linearly and reads with the proven 0-conflict frag formula.
// Also xsq[row] (exact fp32). Scratch lives in prob half of d_out.
// ---------------------------------------------------------------------------
__global__ __launch_bounds__(512) void prep_x(
    const float* __restrict__ x, uint16_t* __restrict__ xh,
    uint16_t* __restrict__ xlo, float* __restrict__ xsq) {
  const int rg = blockIdx.x;        // 0..1023
  const int t  = threadIdx.x;       // 0..511
  const int r  = t >> 2;            // 0..127
  const int q  = t & 3;             // 8-float chunk in 32-k window
  const int row = rg * 128 + r;
  const float* rp = x + (size_t)row * ND + q * 8;
  const int p = q ^ ((r >> 1) & 3);
  const size_t wbase = (size_t)rg * 65536 + (size_t)r * 32 + (size_t)p * 8;
  float ss = 0.f;
#pragma unroll 1
  for (int kk = 0; kk < 16; ++kk) {
    const float* src = rp + kk * 32;
    float4v c0 = *(const float4v*)src;
    float4v c1 = *(const float4v*)(src + 4);
    float v[8] = {c0[0], c0[1], c0[2], c0[3], c1[0], c1[1], c1[2], c1[3]};
    bf16x8 hi, lo;
#pragma unroll
    for (int i = 0; i < 8; ++i) {
      uint16_t hb = f32_bf16(v[i]);
      hi[i] = (short)hb;
      lo[i] = (short)f32_bf16(v[i] - bf16_f32(hb));
      ss += v[i] * v[i];
    }
    *(bf16x8*)(xh  + wbase + (size_t)kk * 4096) = hi;
    *(bf16x8*)(xlo + wbase + (size_t)kk * 4096) = lo;
  }
  ss += __shfl_xor(ss, 1);
  ss += __shfl_xor(ss, 2);
  if (q == 0) xsq[row] = ss;
}

// ---------------------------------------------------------------------------
// Phase 1: distances. 128 rows x 256 cols per block, 512 thr / 8 waves
// (4 wm x 2 wn, wave tile 32x128, acc[2][8] = 64 AGPR). Zero in-loop VALU
// conversion; A and B pre-split bf16, staged linearly via gload_lds
// (4 ops/step), counted vmcnt(4) across raw barriers, proven 0-conflict
// frag swizzle. n-loop split in halves with sched_barrier(0) to cap live
// B-frags at 4 (16 VGPR) -> target total <=128 regs -> 2 blocks/CU.
// Epilogue: ldsT transpose (unions loop smem) -> contiguous float4 stores.
// ---------------------------------------------------------------------------
__global__ __launch_bounds__(512) void kmeans_dist(
    const float* __restrict__ xsq_g,
    const uint16_t* __restrict__ xh, const uint16_t* __restrict__ xlo,
    const uint16_t* __restrict__ cs_hi, const uint16_t* __restrict__ cs_lo,
    const float* __restrict__ csq,
    float* __restrict__ dist) {
  // bs dbuf @0/16384 (16KB each); ahi dbuf @32768 (8KB each); alo dbuf @49152.
  __shared__ __align__(16) char smem[65536];

  const int tid  = threadIdx.x;
  const int lane = tid & 63;
  const int wid  = tid >> 6;        // 0..7
  const int wm   = wid >> 1;        // 0..3 -> rows wm*32
  const int wn   = wid & 1;         // 0..1 -> cols wn*128
  const int rg   = blockIdx.x >> 2; // row group (128 rows)
  const int panel = blockIdx.x & 3; // 256-col panel
  const int row0 = rg * BM;
  const int arow = lane & 15;
  const int kq   = lane >> 4;

  auto stageB = [&](int s) {
    const uint16_t* base = (s < 16) ? cs_hi : cs_lo;
    const char* srcb = (const char*)(base + (size_t)(panel * 16 + (s & 15)) * 8192);
    char* dst = smem + (s & 1) * 16384;
    const int o = tid * 16;
    gload_lds16(srcb + o, dst + o);
    gload_lds16(srcb + o + 8192, dst + o + 8192);
  };
  auto stageA = [&](int s) {
    const size_t off = (size_t)(rg * 16 + (s & 15)) * 8192 + tid * 16;
    gload_lds16((const char*)xh + off,  smem + 32768 + (s & 1) * 8192 + tid * 16);
    gload_lds16((const char*)xlo + off, smem + 49152 + (s & 1) * 8192 + tid * 16);
  };

  f32x4 acc[2][8];
  const f32x4 z = {0.f, 0.f, 0.f, 0.f};
#pragma unroll
  for (int mr = 0; mr < 2; ++mr)
#pragma unroll
    for (int n = 0; n < 8; ++n) acc[mr][n] = z;

  const int swz  = ((kq ^ ((arow >> 1) & 3)) << 4);
  const int boff = (wn * 128 + arow) * 64 + swz;   // + n*1024
  const int aoff = (wm * 32 + arow) * 64 + swz;    // + mr*1024

  // ---- prologue: batch 0 in flight (2 B + 2 A) ----
  stageB(0);
  stageA(0);

#pragma unroll 1
  for (int s = 0; s < NSTEP; ++s) {
    if (s + 1 < NSTEP) {
      stageB(s + 1);
      stageA(s + 1);
      WAITV4();                     // batch s (4 oldest) complete
    } else {
      WAITV0();
    }
    __builtin_amdgcn_s_barrier();   // stage(s) visible to all waves

    {
      const char* bp  = smem + (s & 1) * 16384;
      const char* ahp = smem + 32768 + (s & 1) * 8192;
      bf16x8 ah0 = *(const bf16x8*)(ahp + aoff);
      bf16x8 ah1 = *(const bf16x8*)(ahp + aoff + 1024);
      __builtin_amdgcn_s_setprio(1);
      if (s < 16) {
        const char* alp = smem + 49152 + (s & 1) * 8192;
        bf16x8 al0 = *(const bf16x8*)(alp + aoff);
        bf16x8 al1 = *(const bf16x8*)(alp + aoff + 1024);
#pragma unroll
        for (int n = 0; n < 4; ++n) {
          bf16x8 b = *(const bf16x8*)(bp + boff + n * 1024);
          acc[0][n] = __builtin_amdgcn_mfma_f32_16x16x32_bf16(ah0, b, acc[0][n], 0, 0, 0);
          acc[1][n] = __builtin_amdgcn_mfma_f32_16x16x32_bf16(ah1, b, acc[1][n], 0, 0, 0);
          acc[0][n] = __builtin_amdgcn_mfma_f32_16x16x32_bf16(al0, b, acc[0][n], 0, 0, 0);
          acc[1][n] = __builtin_amdgcn_mfma_f32_16x16x32_bf16(al1, b, acc[1][n], 0, 0, 0);
        }
        __builtin_amdgcn_sched_barrier(0);   // cap live b-frags at 4
#pragma unroll
        for (int n = 4; n < 8; ++n) {
          bf16x8 b = *(const bf16x8*)(bp + boff + n * 1024);
          acc[0][n] = __builtin_amdgcn_mfma_f32_16x16x32_bf16(ah0, b, acc[0][n], 0, 0, 0);
          acc[1][n] = __builtin_amdgcn_mfma_f32_16x16x32_bf16(ah1, b, acc[1][n], 0, 0, 0);
          acc[0][n] = __builtin_amdgcn_mfma_f32_16x16x32_bf16(al0, b, acc[0][n], 0, 0, 0);
          acc[1][n] = __builtin_amdgcn_mfma_f32_16x16x32_bf16(al1, b, acc[1][n], 0, 0, 0);
        }
      } else {
#pragma unroll
        for (int n = 0; n < 4; ++n) {
          bf16x8 b = *(const bf16x8*)(bp + boff + n * 1024);
          acc[0][n] = __builtin_amdgcn_mfma_f32_16x16x32_bf16(ah0, b, acc[0][n], 0, 0, 0);
          acc[1][n] = __builtin_amdgcn_mfma_f32_16x16x32_bf16(ah1, b, acc[1][n], 0, 0, 0);
        }
        __builtin_amdgcn_sched_barrier(0);
#pragma unroll
        for (int n = 4; n < 8; ++n) {
          bf16x8 b = *(const bf16x8*)(bp + boff + n * 1024);
          acc[0][n] = __builtin_amdgcn_mfma_f32_16x16x32_bf16(ah0, b, acc[0][n], 0, 0, 0);
          acc[1][n] = __builtin_amdgcn_mfma_f32_16x16x32_bf16(ah1, b, acc[1][n], 0, 0, 0);
        }
      }
      __builtin_amdgcn_s_setprio(0);
    }
    __builtin_amdgcn_s_barrier();   // reads done before next overwrite
  }

  // csq for this panel (one float4 per lane)
  const float4v cq = *(const float4v*)(csq + panel * BN + lane * 4);

  // ---- epilogue: 4 transpose passes (32 rows each), contiguous stores ----
  float* ldsT = (float*)smem;   // 32 x 258 fp32 = 33KB (unions over loop smem)
  const int rsub = (lane >> 4) * 4;
#pragma unroll
  for (int g = 0; g < 4; ++g) {
    if (wm == g) {
#pragma unroll
      for (int mr = 0; mr < 2; ++mr)
#pragma unroll
        for (int n = 0; n < 8; ++n)
#pragma unroll
          for (int rr = 0; rr < 4; ++rr)
            ldsT[(mr * 16 + rsub + rr) * 258 + wn * 128 + n * 16 + arow] = acc[mr][n][rr];
    }
    __syncthreads();
    {
      const int lr = wid * 4;     // 4 rows per wave
#pragma unroll
      for (int q = 0; q < 4; ++q) {
        const int r = lr + q;
        const float xq = xsq_g[row0 + g * 32 + r];
        const float4v raw = *(const float4v*)&ldsT[r * 258 + lane * 4];
        float4v dd;
#pragma unroll
        for (int i = 0; i < 4; ++i)
          dd[i] = fmaxf(xq + cq[i] - 2.0f * raw[i], 0.0f);
        *(float4v*)(dist + (size_t)(row0 + g * 32 + r) * NC + panel * BN + lane * 4) = dd;
      }
    }
    __syncthreads();
  }
}

// ---------------------------------------------------------------------------
// Phase 2: row softmax(-dist) -> prob. One wave per row, contiguous float4.
// ---------------------------------------------------------------------------
__global__ __launch_bounds__(512) void softmax_rows(
    const float* __restrict__ dist, float* __restrict__ prob) {
  const int tid  = threadIdx.x;
  const int lane = tid & 63;
  const int wid  = tid >> 6;
  const size_t row = (size_t)blockIdx.x * 8 + wid;
  const float* dp = dist + row * NC;
  float* pp = prob + row * NC;

  float4v dd[4];
#pragma unroll
  for (int j = 0; j < 4; ++j)
    dd[j] = *(const float4v*)(dp + lane * 4 + j * 256);

  float dmin = 1e30f;
#pragma unroll
  for (int j = 0; j < 4; ++j)
#pragma unroll
    for (int i = 0; i < 4; ++i) dmin = fminf(dmin, dd[j][i]);
#pragma unroll
  for (int m = 1; m < 64; m <<= 1) dmin = fminf(dmin, __shfl_xor(dmin, m));

  float ssum = 0.f;
#pragma unroll
  for (int j = 0; j < 4; ++j)
#pragma unroll
    for (int i = 0; i < 4; ++i) {
      float e = __expf(dmin - dd[j][i]);
      dd[j][i] = e;
      ssum += e;
    }
#pragma unroll
  for (int m = 1; m < 64; m <<= 1) ssum += __shfl_xor(ssum, m);
  const float sinv = 1.0f / ssum;

#pragma unroll
  for (int j = 0; j < 4; ++j) {
    float4v pv;
#pragma unroll
    for (int i = 0; i < 4; ++i) pv[i] = dd[j][i] * sinv;
    *(float4v*)(pp + lane * 4 + j * 256) = pv;
  }
}

extern "C" void kernel_launch(void* const* d_in, const int* in_sizes, int n_in,
                              void* d_out, int out_size, void* d_ws, size_t ws_size,
                              hipStream_t stream) {
  const float* x = (const float*)d_in[0];
  const float* centers = (const float*)d_in[1];
  float* dist = (float*)d_out;
  float* prob = dist + (size_t)NROWS * NC;

  // x_hi/x_lo/xsq scratch lives in the prob half of d_out (536MB): written by
  // prep_x, consumed by kmeans_dist, then fully overwritten by softmax_rows.
  uint16_t* xh  = (uint16_t*)prob;                       // 134 MB
  uint16_t* xlo = xh + (size_t)NROWS * ND;               // 134 MB
  float* xsq    = (float*)(xlo + (size_t)NROWS * ND);    // 512 KB

  uint16_t* cs_hi = (uint16_t*)d_ws;                     // 1 MB
  uint16_t* cs_lo = cs_hi + (size_t)NC * ND;             // 1 MB
  float* csq = (float*)(cs_lo + (size_t)NC * ND);        // 4 KB

  prep_centers<<<dim3(NC), dim3(64), 0, stream>>>(centers, cs_hi, cs_lo, csq);
  prep_x<<<dim3(NROWS / 128), dim3(512), 0, stream>>>(x, xh, xlo, xsq);
  kmeans_dist<<<dim3((NROWS / BM) * NPANEL), dim3(512), 0, stream>>>(
      xsq, xh, xlo, cs_hi, cs_lo, csq, dist);
  softmax_rows<<<dim3(NROWS / 8), dim3(512), 0, stream>>>(dist, prob);
}